// Round 5
// baseline (591.785 us; speedup 1.0000x reference)
//
#include <hip/hip_runtime.h>
#include <math.h>

#define BN 8192
#define ENC 256
#define NCL 32
#define TM 128

typedef __attribute__((ext_vector_type(8))) short short8;   // bf16x8 fragment
typedef __attribute__((ext_vector_type(4))) float f32x4;
typedef __attribute__((ext_vector_type(4))) unsigned uint4v;

__device__ __forceinline__ ushort f2bf(float x) {           // RNE float->bf16
    unsigned b = __float_as_uint(x);
    return (ushort)((b + 0x7FFFu + ((b >> 16) & 1u)) >> 16);
}

// ---------------- K1: sumsq + cat argmax + bf16 hi/lo split (plain layout) ----------
__global__ void prep_kernel(const float* __restrict__ enc, const float* __restrict__ cat,
                            float* __restrict__ sq, float* __restrict__ maxg,
                            int* __restrict__ hard, ushort* __restrict__ eh,
                            ushort* __restrict__ el) {
    int w = threadIdx.x >> 6, l = threadIdx.x & 63;
    int row = blockIdx.x * 4 + w;
    const float4* e4 = (const float4*)(enc + (size_t)row * ENC);
    float4 v = e4[l];  // elements 4l..4l+3
    float s = v.x * v.x + v.y * v.y + v.z * v.z + v.w * v.w;
    for (int m = 32; m; m >>= 1) s += __shfl_xor(s, m, 64);

    ushort4 hh, ll;
    hh.x = f2bf(v.x); ll.x = f2bf(v.x - __uint_as_float((unsigned)hh.x << 16));
    hh.y = f2bf(v.y); ll.y = f2bf(v.y - __uint_as_float((unsigned)hh.y << 16));
    hh.z = f2bf(v.z); ll.z = f2bf(v.z - __uint_as_float((unsigned)hh.z << 16));
    hh.w = f2bf(v.w); ll.w = f2bf(v.w - __uint_as_float((unsigned)hh.w << 16));
    *(ushort4*)(eh + (size_t)row * ENC + l * 4) = hh;
    *(ushort4*)(el + (size_t)row * ENC + l * 4) = ll;

    float cv = (l < NCL) ? cat[(size_t)row * NCL + l] : -__builtin_huge_valf();
    int ci = (l < NCL) ? l : 0x7fffffff;
    for (int m = 32; m; m >>= 1) {
        float ov = __shfl_xor(cv, m, 64);
        int oi = __shfl_xor(ci, m, 64);
        if (ov > cv || (ov == cv && oi < ci)) { cv = ov; ci = oi; }
    }
    if (l == 0) { sq[row] = s; maxg[row] = cv; hard[row] = ci; }
}

// ---------------- K2: LDS-free split-bf16 MFMA distance GEMM --------------------------
// Fragments load straight from L2 (eh/el = 8 MB, L2-resident): for 16x16x32 bf16
// each lane's A/B fragment is a contiguous 16B global load. No LDS, no barriers,
// no vmcnt-drain stall. Ping-pong register prefetch hides L2 latency under MFMA.
#define LOADK(AH, AL, BH, BL, K0)                                                   \
    do {                                                                            \
        _Pragma("unroll") for (int m_ = 0; m_ < 4; ++m_) {                          \
            size_t ra = (size_t)(gi0 + wm * 64 + m_ * 16 + fr) * ENC + (K0) + ks0;  \
            AH[m_] = *(const short8*)(eh + ra);                                     \
            AL[m_] = *(const short8*)(el + ra);                                     \
        }                                                                           \
        _Pragma("unroll") for (int n_ = 0; n_ < 4; ++n_) {                          \
            size_t rb = (size_t)(j0 + wn * 64 + n_ * 16 + fr) * ENC + (K0) + ks0;   \
            BH[n_] = *(const short8*)(eh + rb);                                     \
            BL[n_] = *(const short8*)(el + rb);                                     \
        }                                                                           \
    } while (0)

#define MFMAK(AH, AL, BH, BL)                                                            \
    do {                                                                                 \
        _Pragma("unroll") for (int m_ = 0; m_ < 4; ++m_)                                 \
        _Pragma("unroll") for (int n_ = 0; n_ < 4; ++n_) {                               \
            acc[m_][n_] = __builtin_amdgcn_mfma_f32_16x16x32_bf16(AH[m_], BH[n_], acc[m_][n_], 0, 0, 0); \
            acc[m_][n_] = __builtin_amdgcn_mfma_f32_16x16x32_bf16(AH[m_], BL[n_], acc[m_][n_], 0, 0, 0); \
            acc[m_][n_] = __builtin_amdgcn_mfma_f32_16x16x32_bf16(AL[m_], BH[n_], acc[m_][n_], 0, 0, 0); \
        }                                                                                \
    } while (0)

__global__ __launch_bounds__(256, 2)
void dist_mfma_kernel(const ushort* __restrict__ eh, const ushort* __restrict__ el,
                      const float* __restrict__ sq, float* __restrict__ dist, int row0) {
    int t = threadIdx.x, w = t >> 6, l = t & 63;
    int wm = w >> 1, wn = w & 1;

    // XCD-chunked bijective swizzle (nwg = 64 * rows/128, always % 8 == 0)
    int nwg = gridDim.x * gridDim.y;
    int bid = blockIdx.y * gridDim.x + blockIdx.x;
    int cpx = nwg >> 3;
    int swz = (bid & 7) * cpx + (bid >> 3);
    int by = swz / gridDim.x, bx = swz - by * gridDim.x;

    int li0 = by * TM;                 // chunk-local A rows (dist)
    int gi0 = row0 + li0;              // global A rows
    int j0 = bx * TM;                  // global B rows / dist cols

    int fr = l & 15;                   // fragment row within 16
    int ks0 = (l >> 4) * 8;            // k-slice within K=32 (8 elems = 16B)

    f32x4 acc[4][4];
#pragma unroll
    for (int m = 0; m < 4; ++m)
#pragma unroll
        for (int n = 0; n < 4; ++n) acc[m][n] = (f32x4){0.f, 0.f, 0.f, 0.f};

    short8 Xah[4], Xal[4], Xbh[4], Xbl[4];
    short8 Yah[4], Yal[4], Ybh[4], Ybl[4];

    LOADK(Xah, Xal, Xbh, Xbl, 0);
#pragma unroll
    for (int ks = 0; ks < 8; ks += 2) {
        if (ks + 1 < 8) LOADK(Yah, Yal, Ybh, Ybl, (ks + 1) * 32);
        MFMAK(Xah, Xal, Xbh, Xbl);
        if (ks + 2 < 8) LOADK(Xah, Xal, Xbh, Xbl, (ks + 2) * 32);
        MFMAK(Yah, Yal, Ybh, Ybl);
    }

    // epilogue: C/D layout col=lane&15, row=(lane>>4)*4+reg (m89-verified)
    float sqi[16], sqj[4];
#pragma unroll
    for (int m = 0; m < 4; ++m)
#pragma unroll
        for (int r = 0; r < 4; ++r)
            sqi[m * 4 + r] = sq[gi0 + wm * 64 + m * 16 + (l >> 4) * 4 + r];
#pragma unroll
    for (int n = 0; n < 4; ++n) sqj[n] = sq[j0 + wn * 64 + n * 16 + (l & 15)];

#pragma unroll
    for (int m = 0; m < 4; ++m)
#pragma unroll
        for (int n = 0; n < 4; ++n)
#pragma unroll
            for (int r = 0; r < 4; ++r) {
                float d2 = sqi[m * 4 + r] + sqj[n] - 2.f * acc[m][n][r];
                size_t off = (size_t)(li0 + wm * 64 + m * 16 + (l >> 4) * 4 + r) * BN
                           + (size_t)(j0 + wn * 64 + n * 16 + (l & 15));
                dist[off] = fmaxf(d2, 0.f);   // clamped d2, no sqrt
            }
}

// ---------------- K3: register-resident rank-26 binary search, one wave per row ------
// asm-volatile loads: compiler CANNOT rematerialize them into the search loop
// (round-2/3 failure mode: VGPR=72, ~26x L2 re-reads of the row, ~200 us).
__global__ __launch_bounds__(256, 2)
void select_kernel(const float* __restrict__ dist, const float* __restrict__ maxg,
                   const int* __restrict__ hard, const int* __restrict__ kptr,
                   float* __restrict__ out, int row0) {
    __shared__ int sbins[4 * NCL];
    int t = threadIdx.x, w = t >> 6, l = t & 63;
    int li = blockIdx.x * 4 + w;       // chunk-local row, one wave per row
    if (l < NCL) sbins[w * NCL + l] = 0;   // own wave's bins only: no barrier

    uint4v U[32];
    const char* rb = (const char*)(dist + (size_t)li * BN) + l * 16;
#pragma unroll
    for (int g = 0; g < 8; ++g) {
        unsigned long long a = (unsigned long long)(rb + g * 4096);
        asm volatile("global_load_dwordx4 %0, %1, off"             : "=v"(U[g * 4 + 0]) : "v"(a));
        asm volatile("global_load_dwordx4 %0, %1, off offset:1024" : "=v"(U[g * 4 + 1]) : "v"(a));
        asm volatile("global_load_dwordx4 %0, %1, off offset:2048" : "=v"(U[g * 4 + 2]) : "v"(a));
        asm volatile("global_load_dwordx4 %0, %1, off offset:3072" : "=v"(U[g * 4 + 3]) : "v"(a));
    }
    asm volatile("s_waitcnt vmcnt(0)" ::: "memory");
    __builtin_amdgcn_sched_barrier(0);  // nothing hoists above the wait (rule #18)

    // row max -> search upper bound; lo=0 exact (d2[i][i]=0). uint order == float
    // order since d2 >= 0.
    unsigned mx = 0u;
#pragma unroll
    for (int e = 0; e < 32; ++e)
#pragma unroll
        for (int c = 0; c < 4; ++c) mx = U[e][c] > mx ? U[e][c] : mx;
    for (int m = 32; m; m >>= 1) {
        unsigned ox = (unsigned)__shfl_xor((int)mx, m, 64);
        mx = ox > mx ? ox : mx;
    }

    int topn = *kptr + 1;  // 26: thr = sorted[k]
    unsigned lo = 0u, hi = mx;
    while (lo < hi) {      // cnt is wave-uniform (ballot) -> scalar branch, no sync
        unsigned mid = lo + ((hi - lo) >> 1);
        int cnt = 0;
#pragma unroll
        for (int e = 0; e < 32; ++e)
#pragma unroll
            for (int c = 0; c < 4; ++c)
                cnt += __popcll(__ballot(U[e][c] <= mid));  // v_cmp + SALU bcnt/add
        if (cnt >= topn) hi = mid; else lo = mid + 1;
    }
    unsigned thrb = lo;    // exact bit pattern of sorted[k] (d2 domain)

    // strict < thrb -> per-cluster counts (rare hits -> wave-local LDS atomics)
#pragma unroll
    for (int g = 0; g < 8; ++g)
#pragma unroll
        for (int o = 0; o < 4; ++o)
#pragma unroll
            for (int c = 0; c < 4; ++c)
                if (U[g * 4 + o][c] < thrb) {
                    int j = g * 1024 + o * 256 + l * 4 + c;
                    atomicAdd(&sbins[w * NCL + hard[j]], 1);
                }
    __syncthreads();       // cheap safety; bins are wave-local

    if (l < NCL) {
        int cnt = sbins[w * NCL + l];
        int n = cnt;
        for (int m = 16; m; m >>= 1) n += __shfl_xor(n, m, 64);
        float nf = (float)n;
        float b = (float)cnt / nf;
        float term = -b * logf(b + 1e-5f);
        for (int m = 16; m; m >>= 1) term += __shfl_xor(term, m, 64);
        if (l == 0) out[row0 + li] = term * maxg[row0 + li];
    }
}

extern "C" void kernel_launch(void* const* d_in, const int* in_sizes, int n_in,
                              void* d_out, int out_size, void* d_ws, size_t ws_size,
                              hipStream_t stream) {
    const float* enc = (const float*)d_in[0];
    const float* cat = (const float*)d_in[1];
    const int* kptr = (const int*)d_in[2];
    float* out = (float*)d_out;

    float* sq = (float*)d_ws;
    float* maxg = sq + BN;
    int* hard = (int*)(maxg + BN);
    ushort* eh = (ushort*)(hard + BN);
    ushort* el = eh + (size_t)BN * ENC;
    float* dist = (float*)(el + (size_t)BN * ENC);

    size_t head = (size_t)((char*)dist - (char*)d_ws);
    size_t avail = ws_size > head ? ws_size - head : 0;
    long max_rows = (long)(avail / ((size_t)BN * sizeof(float)));
    int chunk = (int)((max_rows / TM) * TM);
    if (chunk > BN) chunk = BN;
    if (chunk < TM) chunk = TM;

    prep_kernel<<<BN / 4, 256, 0, stream>>>(enc, cat, sq, maxg, hard, eh, el);

    for (int row0 = 0; row0 < BN; row0 += chunk) {
        int rows = BN - row0 < chunk ? BN - row0 : chunk;
        dim3 g(BN / TM, rows / TM);
        dist_mfma_kernel<<<g, 256, 0, stream>>>(eh, el, sq, dist, row0);
        select_kernel<<<rows / 4, 256, 0, stream>>>(dist, maxg, hard, kptr, out, row0);
    }
}

// Round 6
// 517.736 us; speedup vs baseline: 1.1430x; 1.1430x over previous
//
#include <hip/hip_runtime.h>
#include <math.h>

#define BN 8192
#define ENC 256
#define NCL 32
#define TM 128
#define PANEL 2048

typedef __attribute__((ext_vector_type(8))) short short8;   // bf16x8 fragment
typedef __attribute__((ext_vector_type(4))) float f32x4;
typedef __attribute__((ext_vector_type(4))) unsigned uint4v;

__device__ __forceinline__ ushort f2bf(float x) {           // RNE float->bf16
    unsigned b = __float_as_uint(x);
    return (ushort)((b + 0x7FFFu + ((b >> 16) & 1u)) >> 16);
}

__device__ __forceinline__ void async16(void* lds, const void* g) {
    __builtin_amdgcn_global_load_lds(
        (const __attribute__((address_space(1))) unsigned*)g,
        (__attribute__((address_space(3))) unsigned*)lds, 16, 0, 0);
}

// ---------------- K1: sumsq + cat argmax + bf16 hi/lo split (granule-swizzled) ----------
// Swizzle: within each 64-elem K-step, 16B granule g -> g ^ (row&7); linear
// global_load_lds lands the XOR-swizzled layout in LDS (rule #21).
__global__ void prep_kernel(const float* __restrict__ enc, const float* __restrict__ cat,
                            float* __restrict__ sq, float* __restrict__ maxg,
                            int* __restrict__ hard, ushort* __restrict__ eh,
                            ushort* __restrict__ el) {
    int w = threadIdx.x >> 6, l = threadIdx.x & 63;
    int row = blockIdx.x * 4 + w;
    const float4* e4 = (const float4*)(enc + (size_t)row * ENC);
    float4 v = e4[l];  // elements 4l..4l+3
    float s = v.x * v.x + v.y * v.y + v.z * v.z + v.w * v.w;
    for (int m = 32; m; m >>= 1) s += __shfl_xor(s, m, 64);

    ushort4 hh, ll;
    hh.x = f2bf(v.x); ll.x = f2bf(v.x - __uint_as_float((unsigned)hh.x << 16));
    hh.y = f2bf(v.y); ll.y = f2bf(v.y - __uint_as_float((unsigned)hh.y << 16));
    hh.z = f2bf(v.z); ll.z = f2bf(v.z - __uint_as_float((unsigned)hh.z << 16));
    hh.w = f2bf(v.w); ll.w = f2bf(v.w - __uint_as_float((unsigned)hh.w << 16));
    int g = l >> 1;                                   // original 16B granule 0..31
    int gs = (g & 24) | ((g & 7) ^ (row & 7));        // swizzled granule
    int kp = gs * 8 + (l & 1) * 4;                    // element offset in row
    *(ushort4*)(eh + (size_t)row * ENC + kp) = hh;
    *(ushort4*)(el + (size_t)row * ENC + kp) = ll;

    float cv = (l < NCL) ? cat[(size_t)row * NCL + l] : -__builtin_huge_valf();
    int ci = (l < NCL) ? l : 0x7fffffff;
    for (int m = 32; m; m >>= 1) {
        float ov = __shfl_xor(cv, m, 64);
        int oi = __shfl_xor(ci, m, 64);
        if (ov > cv || (ov == cv && oi < ci)) { cv = ov; ci = oi; }
    }
    if (l == 0) { sq[row] = s; maxg[row] = cv; hard[row] = ci; }
}

// ---------------- K2: split-bf16 MFMA distance GEMM (LDS-staged, swapped C-layout) ----
// dot = hi.hi + hi.lo + lo.hi (lo.lo dropped, ~2^-18 rel). 128x128 tile, BK=64,
// 4 waves (2x2). MFMA operands SWAPPED (b, a): lane then holds 4 CONSECUTIVE dist
// cols of one row -> float4 stores (64B sector-complete segments), no
// write-allocate fetch (round-5 lesson: scalar stores = 266 MB HBM fetch).
__global__ __launch_bounds__(256, 2)
void dist_mfma_kernel(const ushort* __restrict__ eh, const ushort* __restrict__ el,
                      const float* __restrict__ sq, float* __restrict__ dist, int row0) {
    __shared__ __align__(16) ushort lds[4 * TM * 64];  // 64 KB: Ah Al Bh Bl
    ushort* Ah = lds;
    ushort* Al = lds + TM * 64;
    ushort* Bh = lds + 2 * TM * 64;
    ushort* Bl = lds + 3 * TM * 64;

    int t = threadIdx.x, w = t >> 6, l = t & 63;
    int wm = w >> 1, wn = w & 1;

    // XCD-chunked bijective swizzle (nwg = 64 * rows/128, always % 8 == 0)
    int nwg = gridDim.x * gridDim.y;
    int bid = blockIdx.y * gridDim.x + blockIdx.x;
    int cpx = nwg >> 3;
    int swz = (bid & 7) * cpx + (bid >> 3);
    int by = swz / gridDim.x, bx = swz - by * gridDim.x;

    int li0 = by * TM;                 // chunk-local A rows (dist)
    int gi0 = row0 + li0;              // global A rows
    int j0 = bx * TM;                  // global B rows / dist cols

    f32x4 acc[4][4];
#pragma unroll
    for (int m = 0; m < 4; ++m)
#pragma unroll
        for (int n = 0; n < 4; ++n) acc[m][n] = (f32x4){0.f, 0.f, 0.f, 0.f};

    int srow = w * 32 + (l >> 3);      // staging row (+ q*8), wave covers 32 rows
    int selem = (l & 7) * 8;           // granule elem offset within K-step slice

    for (int k0 = 0; k0 < ENC; k0 += 64) {
        __syncthreads();               // LDS reads of previous step done
#pragma unroll
        for (int q = 0; q < 4; ++q) {
            int r = srow + q * 8;
            size_t ga = (size_t)(gi0 + r) * ENC + k0 + selem;
            size_t gb = (size_t)(j0 + r) * ENC + k0 + selem;
            int ldo = (w * 4 + q) * 512;  // ushort offset: 64 lanes x 16B
            async16(Ah + ldo, eh + ga);
            async16(Al + ldo, el + ga);
            async16(Bh + ldo, eh + gb);
            async16(Bl + ldo, el + gb);
        }
        __syncthreads();               // drains vmcnt (compiler) -> tiles ready

#pragma unroll
        for (int h = 0; h < 2; ++h) {  // two K=32 halves of the K-step
            short8 ah[4], al4[4], bh[4], bl4[4];
#pragma unroll
            for (int m = 0; m < 4; ++m) {
                int R = wm * 64 + m * 16 + (l & 15);
                int gq = (h * 4 + (l >> 4)) ^ (R & 7);   // un-swizzle on read
                ah[m]  = *(const short8*)(Ah + R * 64 + gq * 8);
                al4[m] = *(const short8*)(Al + R * 64 + gq * 8);
            }
#pragma unroll
            for (int n = 0; n < 4; ++n) {
                int R = wn * 64 + n * 16 + (l & 15);
                int gq = (h * 4 + (l >> 4)) ^ (R & 7);
                bh[n]  = *(const short8*)(Bh + R * 64 + gq * 8);
                bl4[n] = *(const short8*)(Bl + R * 64 + gq * 8);
            }
            // swapped operands: D[col=l&15 -> dist row][reg -> dist col]
#pragma unroll
            for (int m = 0; m < 4; ++m)
#pragma unroll
                for (int n = 0; n < 4; ++n) {
                    acc[m][n] = __builtin_amdgcn_mfma_f32_16x16x32_bf16(bh[n],  ah[m],  acc[m][n], 0, 0, 0);
                    acc[m][n] = __builtin_amdgcn_mfma_f32_16x16x32_bf16(bl4[n], ah[m],  acc[m][n], 0, 0, 0);
                    acc[m][n] = __builtin_amdgcn_mfma_f32_16x16x32_bf16(bh[n],  al4[m], acc[m][n], 0, 0, 0);
                }
        }
    }

    // epilogue (swapped layout): i = base + m*16 + (l&15), j = base + n*16 + (l>>4)*4 + r
    int il = l & 15, q4 = (l >> 4) * 4;
    float sqi[4];
    float sqj[4][4];
#pragma unroll
    for (int m = 0; m < 4; ++m) sqi[m] = sq[gi0 + wm * 64 + m * 16 + il];
#pragma unroll
    for (int n = 0; n < 4; ++n)
#pragma unroll
        for (int r = 0; r < 4; ++r) sqj[n][r] = sq[j0 + wn * 64 + n * 16 + q4 + r];

#pragma unroll
    for (int m = 0; m < 4; ++m)
#pragma unroll
        for (int n = 0; n < 4; ++n) {
            float4 o;
            o.x = fmaxf(sqi[m] + sqj[n][0] - 2.f * acc[m][n][0], 0.f);
            o.y = fmaxf(sqi[m] + sqj[n][1] - 2.f * acc[m][n][1], 0.f);
            o.z = fmaxf(sqi[m] + sqj[n][2] - 2.f * acc[m][n][2], 0.f);
            o.w = fmaxf(sqi[m] + sqj[n][3] - 2.f * acc[m][n][3], 0.f);
            *(float4*)(dist + (size_t)(li0 + wm * 64 + m * 16 + il) * BN
                            + j0 + wn * 64 + n * 16 + q4) = o;
        }
}

// ---------------- K3: register-resident rank-26 binary search, one wave per row ------
// asm-volatile loads: compiler cannot rematerialize them into the search loop
// (round-2/3 failure mode). Panel is L3-hot (just written by GEMM).
__global__ __launch_bounds__(256, 2)
void select_kernel(const float* __restrict__ dist, const float* __restrict__ maxg,
                   const int* __restrict__ hard, const int* __restrict__ kptr,
                   float* __restrict__ out, int row0) {
    __shared__ int sbins[4 * NCL];
    int t = threadIdx.x, w = t >> 6, l = t & 63;
    int li = blockIdx.x * 4 + w;       // chunk-local row, one wave per row
    if (l < NCL) sbins[w * NCL + l] = 0;   // own wave's bins only: no barrier

    uint4v U[32];
    const char* rb = (const char*)(dist + (size_t)li * BN) + l * 16;
#pragma unroll
    for (int g = 0; g < 8; ++g) {
        unsigned long long a = (unsigned long long)(rb + g * 4096);
        asm volatile("global_load_dwordx4 %0, %1, off"             : "=v"(U[g * 4 + 0]) : "v"(a));
        asm volatile("global_load_dwordx4 %0, %1, off offset:1024" : "=v"(U[g * 4 + 1]) : "v"(a));
        asm volatile("global_load_dwordx4 %0, %1, off offset:2048" : "=v"(U[g * 4 + 2]) : "v"(a));
        asm volatile("global_load_dwordx4 %0, %1, off offset:3072" : "=v"(U[g * 4 + 3]) : "v"(a));
    }
    asm volatile("s_waitcnt vmcnt(0)" ::: "memory");
    __builtin_amdgcn_sched_barrier(0);  // nothing hoists above the wait (rule #18)

    // row max -> search upper bound; lo=0 exact (d2[i][i]=0). uint order == float
    // order since d2 >= 0.
    unsigned mx = 0u;
#pragma unroll
    for (int e = 0; e < 32; ++e)
#pragma unroll
        for (int c = 0; c < 4; ++c) mx = U[e][c] > mx ? U[e][c] : mx;
    for (int m = 32; m; m >>= 1) {
        unsigned ox = (unsigned)__shfl_xor((int)mx, m, 64);
        mx = ox > mx ? ox : mx;
    }

    int topn = *kptr + 1;  // 26: thr = sorted[k]
    unsigned lo = 0u, hi = mx;
    while (lo < hi) {      // cnt is wave-uniform (ballot) -> scalar branch, no sync
        unsigned mid = lo + ((hi - lo) >> 1);
        int cnt = 0;
#pragma unroll
        for (int e = 0; e < 32; ++e)
#pragma unroll
            for (int c = 0; c < 4; ++c)
                cnt += __popcll(__ballot(U[e][c] <= mid));  // v_cmp + SALU bcnt/add
        if (cnt >= topn) hi = mid; else lo = mid + 1;
    }
    unsigned thrb = lo;    // exact bit pattern of sorted[k] (d2 domain)

    // strict < thrb -> per-cluster counts (rare hits -> wave-local LDS atomics)
#pragma unroll
    for (int g = 0; g < 8; ++g)
#pragma unroll
        for (int o = 0; o < 4; ++o)
#pragma unroll
            for (int c = 0; c < 4; ++c)
                if (U[g * 4 + o][c] < thrb) {
                    int j = g * 1024 + o * 256 + l * 4 + c;
                    atomicAdd(&sbins[w * NCL + hard[j]], 1);
                }
    __syncthreads();       // cheap safety; bins are wave-local

    if (l < NCL) {
        int cnt = sbins[w * NCL + l];
        int n = cnt;
        for (int m = 16; m; m >>= 1) n += __shfl_xor(n, m, 64);
        float nf = (float)n;
        float b = (float)cnt / nf;
        float term = -b * logf(b + 1e-5f);
        for (int m = 16; m; m >>= 1) term += __shfl_xor(term, m, 64);
        if (l == 0) out[row0 + li] = term * maxg[row0 + li];
    }
}

extern "C" void kernel_launch(void* const* d_in, const int* in_sizes, int n_in,
                              void* d_out, int out_size, void* d_ws, size_t ws_size,
                              hipStream_t stream) {
    const float* enc = (const float*)d_in[0];
    const float* cat = (const float*)d_in[1];
    const int* kptr = (const int*)d_in[2];
    float* out = (float*)d_out;

    float* sq = (float*)d_ws;
    float* maxg = sq + BN;
    int* hard = (int*)(maxg + BN);
    ushort* eh = (ushort*)(hard + BN);
    ushort* el = eh + (size_t)BN * ENC;
    float* dist = (float*)(el + (size_t)BN * ENC);

    // Panel-cycle dist through L3: 2048x8192 fp32 = 64 MB buffer reused 4x, so
    // GEMM writes stay L3-resident for the immediately-following select reads
    // and the same lines are re-dirtied in place next panel (no 268 MB HBM
    // round trip). Shrink panel if workspace is tight.
    size_t head = (size_t)((char*)dist - (char*)d_ws);
    size_t avail = ws_size > head ? ws_size - head : 0;
    long max_rows = (long)(avail / ((size_t)BN * sizeof(float)));
    int chunk = PANEL;
    if (chunk > max_rows) chunk = (int)((max_rows / TM) * TM);
    if (chunk > BN) chunk = BN;
    if (chunk < TM) chunk = TM;

    prep_kernel<<<BN / 4, 256, 0, stream>>>(enc, cat, sq, maxg, hard, eh, el);

    for (int row0 = 0; row0 < BN; row0 += chunk) {
        int rows = BN - row0 < chunk ? BN - row0 : chunk;
        dim3 g(BN / TM, rows / TM);
        dist_mfma_kernel<<<g, 256, 0, stream>>>(eh, el, sq, dist, row0);
        select_kernel<<<rows / 4, 256, 0, stream>>>(dist, maxg, hard, kptr, out, row0);
    }
}

// Round 7
// 411.581 us; speedup vs baseline: 1.4378x; 1.2579x over previous
//
#include <hip/hip_runtime.h>
#include <math.h>

#define BN 8192
#define ENC 256
#define NCL 32
#define TM 128
#define PANEL 2048

typedef __attribute__((ext_vector_type(8))) short short8;   // bf16x8 fragment
typedef __attribute__((ext_vector_type(4))) float f32x4;
typedef __attribute__((ext_vector_type(4))) unsigned uint4v;

__device__ __forceinline__ ushort f2bf(float x) {           // RNE float->bf16
    unsigned b = __float_as_uint(x);
    return (ushort)((b + 0x7FFFu + ((b >> 16) & 1u)) >> 16);
}

__device__ __forceinline__ void async16(void* lds, const void* g) {
    __builtin_amdgcn_global_load_lds(
        (const __attribute__((address_space(1))) unsigned*)g,
        (__attribute__((address_space(3))) unsigned*)lds, 16, 0, 0);
}

// ---------------- K1: sumsq + cat argmax + bf16 hi/lo split (granule-swizzled) ----------
// Swizzle: within each 64-elem K-step, 16B granule g -> g ^ (row&7); linear
// global_load_lds lands the XOR-swizzled layout in LDS (rule #21).
__global__ void prep_kernel(const float* __restrict__ enc, const float* __restrict__ cat,
                            float* __restrict__ sq, float* __restrict__ maxg,
                            int* __restrict__ hard, ushort* __restrict__ eh,
                            ushort* __restrict__ el) {
    int w = threadIdx.x >> 6, l = threadIdx.x & 63;
    int row = blockIdx.x * 4 + w;
    const float4* e4 = (const float4*)(enc + (size_t)row * ENC);
    float4 v = e4[l];  // elements 4l..4l+3
    float s = v.x * v.x + v.y * v.y + v.z * v.z + v.w * v.w;
    for (int m = 32; m; m >>= 1) s += __shfl_xor(s, m, 64);

    ushort4 hh, ll;
    hh.x = f2bf(v.x); ll.x = f2bf(v.x - __uint_as_float((unsigned)hh.x << 16));
    hh.y = f2bf(v.y); ll.y = f2bf(v.y - __uint_as_float((unsigned)hh.y << 16));
    hh.z = f2bf(v.z); ll.z = f2bf(v.z - __uint_as_float((unsigned)hh.z << 16));
    hh.w = f2bf(v.w); ll.w = f2bf(v.w - __uint_as_float((unsigned)hh.w << 16));
    int g = l >> 1;                                   // original 16B granule 0..31
    int gs = (g & 24) | ((g & 7) ^ (row & 7));        // swizzled granule
    int kp = gs * 8 + (l & 1) * 4;                    // element offset in row
    *(ushort4*)(eh + (size_t)row * ENC + kp) = hh;
    *(ushort4*)(el + (size_t)row * ENC + kp) = ll;

    float cv = (l < NCL) ? cat[(size_t)row * NCL + l] : -__builtin_huge_valf();
    int ci = (l < NCL) ? l : 0x7fffffff;
    for (int m = 32; m; m >>= 1) {
        float ov = __shfl_xor(cv, m, 64);
        int oi = __shfl_xor(ci, m, 64);
        if (ov > cv || (ov == cv && oi < ci)) { cv = ov; ci = oi; }
    }
    if (l == 0) { sq[row] = s; maxg[row] = cv; hard[row] = ci; }
}

// ---------------- K2: split-bf16 MFMA distance GEMM (LDS-staged, swapped C-layout) ----
// dot = hi.hi + hi.lo + lo.hi (lo.lo dropped, ~2^-18 rel). 128x128 tile, BK=64,
// 4 waves (2x2). MFMA operands SWAPPED (b, a): lane holds 4 CONSECUTIVE dist
// cols of one row -> float4 stores (sector-complete), no write-allocate fetch.
__global__ __launch_bounds__(256, 2)
void dist_mfma_kernel(const ushort* __restrict__ eh, const ushort* __restrict__ el,
                      const float* __restrict__ sq, float* __restrict__ dist, int row0) {
    __shared__ __align__(16) ushort lds[4 * TM * 64];  // 64 KB: Ah Al Bh Bl
    ushort* Ah = lds;
    ushort* Al = lds + TM * 64;
    ushort* Bh = lds + 2 * TM * 64;
    ushort* Bl = lds + 3 * TM * 64;

    int t = threadIdx.x, w = t >> 6, l = t & 63;
    int wm = w >> 1, wn = w & 1;

    // XCD-chunked bijective swizzle (nwg = 64 * rows/128, always % 8 == 0)
    int nwg = gridDim.x * gridDim.y;
    int bid = blockIdx.y * gridDim.x + blockIdx.x;
    int cpx = nwg >> 3;
    int swz = (bid & 7) * cpx + (bid >> 3);
    int by = swz / gridDim.x, bx = swz - by * gridDim.x;

    int li0 = by * TM;                 // chunk-local A rows (dist)
    int gi0 = row0 + li0;              // global A rows
    int j0 = bx * TM;                  // global B rows / dist cols

    f32x4 acc[4][4];
#pragma unroll
    for (int m = 0; m < 4; ++m)
#pragma unroll
        for (int n = 0; n < 4; ++n) acc[m][n] = (f32x4){0.f, 0.f, 0.f, 0.f};

    int srow = w * 32 + (l >> 3);      // staging row (+ q*8), wave covers 32 rows
    int selem = (l & 7) * 8;           // granule elem offset within K-step slice

    for (int k0 = 0; k0 < ENC; k0 += 64) {
        __syncthreads();               // LDS reads of previous step done
#pragma unroll
        for (int q = 0; q < 4; ++q) {
            int r = srow + q * 8;
            size_t ga = (size_t)(gi0 + r) * ENC + k0 + selem;
            size_t gb = (size_t)(j0 + r) * ENC + k0 + selem;
            int ldo = (w * 4 + q) * 512;  // ushort offset: 64 lanes x 16B
            async16(Ah + ldo, eh + ga);
            async16(Al + ldo, el + ga);
            async16(Bh + ldo, eh + gb);
            async16(Bl + ldo, el + gb);
        }
        __syncthreads();               // drains vmcnt (compiler) -> tiles ready

#pragma unroll
        for (int h = 0; h < 2; ++h) {  // two K=32 halves of the K-step
            short8 ah[4], al4[4], bh[4], bl4[4];
#pragma unroll
            for (int m = 0; m < 4; ++m) {
                int R = wm * 64 + m * 16 + (l & 15);
                int gq = (h * 4 + (l >> 4)) ^ (R & 7);   // un-swizzle on read
                ah[m]  = *(const short8*)(Ah + R * 64 + gq * 8);
                al4[m] = *(const short8*)(Al + R * 64 + gq * 8);
            }
#pragma unroll
            for (int n = 0; n < 4; ++n) {
                int R = wn * 64 + n * 16 + (l & 15);
                int gq = (h * 4 + (l >> 4)) ^ (R & 7);
                bh[n]  = *(const short8*)(Bh + R * 64 + gq * 8);
                bl4[n] = *(const short8*)(Bl + R * 64 + gq * 8);
            }
            // swapped operands: D[col=l&15 -> dist row][reg -> dist col]
#pragma unroll
            for (int m = 0; m < 4; ++m)
#pragma unroll
                for (int n = 0; n < 4; ++n) {
                    acc[m][n] = __builtin_amdgcn_mfma_f32_16x16x32_bf16(bh[n],  ah[m],  acc[m][n], 0, 0, 0);
                    acc[m][n] = __builtin_amdgcn_mfma_f32_16x16x32_bf16(bl4[n], ah[m],  acc[m][n], 0, 0, 0);
                    acc[m][n] = __builtin_amdgcn_mfma_f32_16x16x32_bf16(bh[n],  al4[m], acc[m][n], 0, 0, 0);
                }
        }
    }

    // epilogue (swapped layout): i = base + m*16 + (l&15), j = base + n*16 + (l>>4)*4 + r
    int il = l & 15, q4 = (l >> 4) * 4;
    float sqi[4];
    float sqj[4][4];
#pragma unroll
    for (int m = 0; m < 4; ++m) sqi[m] = sq[gi0 + wm * 64 + m * 16 + il];
#pragma unroll
    for (int n = 0; n < 4; ++n)
#pragma unroll
        for (int r = 0; r < 4; ++r) sqj[n][r] = sq[j0 + wn * 64 + n * 16 + q4 + r];

#pragma unroll
    for (int m = 0; m < 4; ++m)
#pragma unroll
        for (int n = 0; n < 4; ++n) {
            float4 o;
            o.x = fmaxf(sqi[m] + sqj[n][0] - 2.f * acc[m][n][0], 0.f);
            o.y = fmaxf(sqi[m] + sqj[n][1] - 2.f * acc[m][n][1], 0.f);
            o.z = fmaxf(sqi[m] + sqj[n][2] - 2.f * acc[m][n][2], 0.f);
            o.w = fmaxf(sqi[m] + sqj[n][3] - 2.f * acc[m][n][3], 0.f);
            *(float4*)(dist + (size_t)(li0 + wm * 64 + m * 16 + il) * BN
                            + j0 + wn * 64 + n * 16 + q4) = o;
        }
}

// ---------------- K3: rank-26 select, ONE ROW PER BLOCK, 32 values/lane ---------------
// Live set = 8 uint4v = 32 VGPRs per lane: no remat incentive, no spill (rounds
// 2-6 lesson: 128-value live sets get rematerialized or spilled, ~5x cost).
// One barrier per search iteration via parity-double-buffered partial counts.
__global__ __launch_bounds__(256, 4)
void select_kernel(const float* __restrict__ dist, const float* __restrict__ maxg,
                   const int* __restrict__ hard, const int* __restrict__ kptr,
                   float* __restrict__ out, int row0) {
    __shared__ int scnt[2][4];
    __shared__ unsigned swmax[4];
    __shared__ int sbins[NCL];

    int t = threadIdx.x, w = t >> 6, l = t & 63;
    int li = blockIdx.x;               // chunk-local row (one block per row)
    if (t < NCL) sbins[t] = 0;

    uint4v U[8];
    const uint4v* rd = (const uint4v*)(dist + (size_t)li * BN);
#pragma unroll
    for (int q = 0; q < 8; ++q) U[q] = rd[q * 256 + t];

    // block max -> search upper bound (d2 >= 0: uint order == float order)
    unsigned mx = 0u;
#pragma unroll
    for (int q = 0; q < 8; ++q)
#pragma unroll
        for (int c = 0; c < 4; ++c) mx = U[q][c] > mx ? U[q][c] : mx;
    for (int m = 32; m; m >>= 1) {
        unsigned ox = (unsigned)__shfl_xor((int)mx, m, 64);
        mx = ox > mx ? ox : mx;
    }
    if (l == 0) swmax[w] = mx;
    __syncthreads();
    mx = swmax[0];
    mx = swmax[1] > mx ? swmax[1] : mx;
    mx = swmax[2] > mx ? swmax[2] : mx;
    mx = swmax[3] > mx ? swmax[3] : mx;

    int topn = *kptr + 1;              // 26: thr = sorted[k]
    unsigned lo = 0u, hi = mx;
    int p = 0;
    while (lo < hi) {                  // lo/hi/tot block-uniform -> barrier legal
        unsigned mid = lo + ((hi - lo) >> 1);
        int cnt = 0;
#pragma unroll
        for (int q = 0; q < 8; ++q)
#pragma unroll
            for (int c = 0; c < 4; ++c)
                cnt += __popcll(__ballot(U[q][c] <= mid));  // v_cmp + SALU bcnt
        if (l == 0) scnt[p][w] = cnt;
        __syncthreads();               // slot p visible; p^1 writes can't collide
        int tot = scnt[p][0] + scnt[p][1] + scnt[p][2] + scnt[p][3];
        if (tot >= topn) hi = mid; else lo = mid + 1;
        p ^= 1;
    }
    unsigned thrb = lo;                // exact bit pattern of sorted[k] (d2 domain)

    // strict < thrb -> per-cluster counts (~26 hits/row -> rare LDS atomics)
#pragma unroll
    for (int q = 0; q < 8; ++q)
#pragma unroll
        for (int c = 0; c < 4; ++c)
            if (U[q][c] < thrb) {
                int j = (q * 256 + t) * 4 + c;
                atomicAdd(&sbins[hard[j]], 1);
            }
    __syncthreads();

    // entropy epilogue: wave 0, lanes 0..31 = clusters
    if (t < NCL) {
        int cnt = sbins[t];
        int n = cnt;
        for (int m = 16; m; m >>= 1) n += __shfl_xor(n, m, 64);
        float nf = (float)n;
        float b = (float)cnt / nf;
        float term = -b * logf(b + 1e-5f);
        for (int m = 16; m; m >>= 1) term += __shfl_xor(term, m, 64);
        if (t == 0) out[row0 + li] = term * maxg[row0 + li];
    }
}

extern "C" void kernel_launch(void* const* d_in, const int* in_sizes, int n_in,
                              void* d_out, int out_size, void* d_ws, size_t ws_size,
                              hipStream_t stream) {
    const float* enc = (const float*)d_in[0];
    const float* cat = (const float*)d_in[1];
    const int* kptr = (const int*)d_in[2];
    float* out = (float*)d_out;

    float* sq = (float*)d_ws;
    float* maxg = sq + BN;
    int* hard = (int*)(maxg + BN);
    ushort* eh = (ushort*)(hard + BN);
    ushort* el = eh + (size_t)BN * ENC;
    float* dist = (float*)(el + (size_t)BN * ENC);

    // Panel-cycle dist through L3: 2048x8192 fp32 = 64 MB buffer reused 4x, so
    // GEMM writes stay L3-resident for the immediately-following select reads.
    size_t head = (size_t)((char*)dist - (char*)d_ws);
    size_t avail = ws_size > head ? ws_size - head : 0;
    long max_rows = (long)(avail / ((size_t)BN * sizeof(float)));
    int chunk = PANEL;
    if (chunk > max_rows) chunk = (int)((max_rows / TM) * TM);
    if (chunk > BN) chunk = BN;
    if (chunk < TM) chunk = TM;

    prep_kernel<<<BN / 4, 256, 0, stream>>>(enc, cat, sq, maxg, hard, eh, el);

    for (int row0 = 0; row0 < BN; row0 += chunk) {
        int rows = BN - row0 < chunk ? BN - row0 : chunk;
        dim3 g(BN / TM, rows / TM);
        dist_mfma_kernel<<<g, 256, 0, stream>>>(eh, el, sq, dist, row0);
        select_kernel<<<rows, 256, 0, stream>>>(dist, maxg, hard, kptr, out, row0);
    }
}

// Round 8
// 402.794 us; speedup vs baseline: 1.4692x; 1.0218x over previous
//
#include <hip/hip_runtime.h>
#include <math.h>

#define BN 8192
#define ENC 256
#define NCL 32
#define TM 128
#define BK 32
#define PANEL 2048

typedef __attribute__((ext_vector_type(8))) short short8;   // bf16x8 fragment
typedef __attribute__((ext_vector_type(4))) float f32x4;
typedef __attribute__((ext_vector_type(4))) unsigned uint4v;

__device__ __forceinline__ ushort f2bf(float x) {           // RNE float->bf16
    unsigned b = __float_as_uint(x);
    return (ushort)((b + 0x7FFFu + ((b >> 16) & 1u)) >> 16);
}

__device__ __forceinline__ void async16(void* lds, const void* g) {
    __builtin_amdgcn_global_load_lds(
        (const __attribute__((address_space(1))) unsigned*)g,
        (__attribute__((address_space(3))) unsigned*)lds, 16, 0, 0);
}

// ---------------- K1: sumsq + cat argmax + bf16 hi/lo split (granule-swizzled) ----------
// Swizzle for BK=32: within each 32-elem K-slice (4 granules of 16B), granule
// g -> g ^ ((row>>1)&3). Read-side applies the same XOR; lanes sharing a k-slice
// then hit all 8 {granule, row-parity} bank slots -> 2-way only (free, m136).
__global__ void prep_kernel(const float* __restrict__ enc, const float* __restrict__ cat,
                            float* __restrict__ sq, float* __restrict__ maxg,
                            int* __restrict__ hard, ushort* __restrict__ eh,
                            ushort* __restrict__ el) {
    int w = threadIdx.x >> 6, l = threadIdx.x & 63;
    int row = blockIdx.x * 4 + w;
    const float4* e4 = (const float4*)(enc + (size_t)row * ENC);
    float4 v = e4[l];  // elements 4l..4l+3
    float s = v.x * v.x + v.y * v.y + v.z * v.z + v.w * v.w;
    for (int m = 32; m; m >>= 1) s += __shfl_xor(s, m, 64);

    ushort4 hh, ll;
    hh.x = f2bf(v.x); ll.x = f2bf(v.x - __uint_as_float((unsigned)hh.x << 16));
    hh.y = f2bf(v.y); ll.y = f2bf(v.y - __uint_as_float((unsigned)hh.y << 16));
    hh.z = f2bf(v.z); ll.z = f2bf(v.z - __uint_as_float((unsigned)hh.z << 16));
    hh.w = f2bf(v.w); ll.w = f2bf(v.w - __uint_as_float((unsigned)hh.w << 16));
    int g = l >> 1;                                       // original granule 0..31
    int gs = (g & ~3) | ((g & 3) ^ ((row >> 1) & 3));     // swizzled within group-of-4
    int kp = gs * 8 + (l & 1) * 4;                        // element offset in row
    *(ushort4*)(eh + (size_t)row * ENC + kp) = hh;
    *(ushort4*)(el + (size_t)row * ENC + kp) = ll;

    float cv = (l < NCL) ? cat[(size_t)row * NCL + l] : -__builtin_huge_valf();
    int ci = (l < NCL) ? l : 0x7fffffff;
    for (int m = 32; m; m >>= 1) {
        float ov = __shfl_xor(cv, m, 64);
        int oi = __shfl_xor(ci, m, 64);
        if (ov > cv || (ov == cv && oi < ci)) { cv = ov; ci = oi; }
    }
    if (l == 0) { sq[row] = s; maxg[row] = cv; hard[row] = ci; }
}

// ---------------- K2: pipelined split-bf16 MFMA distance GEMM -------------------------
// 2-phase pipeline (T3 minimum): double-buffered LDS, BK=32, 8 K-steps. STAGE of
// step k+1 is issued BEFORE computing step k; the single per-step barrier's
// vmcnt drain then waits on loads that had the whole MFMA phase to land
// (round-7 structure paid full stage latency on the critical path every step).
// MFMA operands swapped (b, a): lane holds 4 consecutive dist cols -> float4
// stores (sector-complete, no write-allocate fetch).
__global__ __launch_bounds__(256, 2)
void dist_mfma_kernel(const ushort* __restrict__ eh, const ushort* __restrict__ el,
                      const float* __restrict__ sq, float* __restrict__ dist, int row0) {
    __shared__ __align__(16) ushort lds[2][4 * TM * BK];  // 2 bufs x 32KB (Ah Al Bh Bl)

    int t = threadIdx.x, w = t >> 6, l = t & 63;
    int wm = w >> 1, wn = w & 1;

    // XCD-chunked bijective swizzle (nwg = 64 * rows/128, always % 8 == 0)
    int nwg = gridDim.x * gridDim.y;
    int bid = blockIdx.y * gridDim.x + blockIdx.x;
    int cpx = nwg >> 3;
    int swz = (bid & 7) * cpx + (bid >> 3);
    int by = swz / gridDim.x, bx = swz - by * gridDim.x;

    int li0 = by * TM;                 // chunk-local A rows (dist)
    int gi0 = row0 + li0;              // global A rows
    int j0 = bx * TM;                  // global B rows / dist cols

    f32x4 acc[4][4];
#pragma unroll
    for (int m = 0; m < 4; ++m)
#pragma unroll
        for (int n = 0; n < 4; ++n) acc[m][n] = (f32x4){0.f, 0.f, 0.f, 0.f};

    int srow = w * 32 + (l >> 2);      // staging row (+ q*16), wave covers 32 rows
    int sg = (l & 3) * 8;              // granule elem offset within K-slice

#define STAGE(BUF, K0)                                                       \
    do {                                                                     \
        _Pragma("unroll") for (int q_ = 0; q_ < 2; ++q_) {                   \
            int r_ = srow + q_ * 16;                                         \
            size_t ga_ = (size_t)(gi0 + r_) * ENC + (K0) + sg;               \
            size_t gb_ = (size_t)(j0 + r_) * ENC + (K0) + sg;                \
            int ldo_ = r_ * BK + sg;  /* byte = r*64 + (l&3)*16: lane-linear */ \
            async16(&lds[BUF][0 * TM * BK + ldo_], eh + ga_);                \
            async16(&lds[BUF][1 * TM * BK + ldo_], el + ga_);                \
            async16(&lds[BUF][2 * TM * BK + ldo_], eh + gb_);                \
            async16(&lds[BUF][3 * TM * BK + ldo_], el + gb_);                \
        }                                                                    \
    } while (0)

    STAGE(0, 0);
    __syncthreads();                   // prologue: wait first tile (full latency once)

    int cur = 0;
    for (int k0 = 0; k0 < ENC; k0 += BK) {
        if (k0 + BK < ENC) STAGE(cur ^ 1, k0 + BK);   // issue next tile FIRST

        const ushort* Ah = &lds[cur][0];
        const ushort* Al = Ah + TM * BK;
        const ushort* Bh = Ah + 2 * TM * BK;
        const ushort* Bl = Ah + 3 * TM * BK;

        short8 ah[4], al4[4], bh[4], bl4[4];
#pragma unroll
        for (int m = 0; m < 4; ++m) {
            int R = wm * 64 + m * 16 + (l & 15);
            int gl = (l >> 4) ^ ((R >> 1) & 3);       // un-swizzle on read
            ah[m]  = *(const short8*)(Ah + R * BK + gl * 8);
            al4[m] = *(const short8*)(Al + R * BK + gl * 8);
        }
#pragma unroll
        for (int n = 0; n < 4; ++n) {
            int R = wn * 64 + n * 16 + (l & 15);
            int gl = (l >> 4) ^ ((R >> 1) & 3);
            bh[n]  = *(const short8*)(Bh + R * BK + gl * 8);
            bl4[n] = *(const short8*)(Bl + R * BK + gl * 8);
        }
        // swapped operands: D[col=l&15 -> dist row][reg -> dist col]
#pragma unroll
        for (int m = 0; m < 4; ++m)
#pragma unroll
            for (int n = 0; n < 4; ++n) {
                acc[m][n] = __builtin_amdgcn_mfma_f32_16x16x32_bf16(bh[n],  ah[m],  acc[m][n], 0, 0, 0);
                acc[m][n] = __builtin_amdgcn_mfma_f32_16x16x32_bf16(bl4[n], ah[m],  acc[m][n], 0, 0, 0);
                acc[m][n] = __builtin_amdgcn_mfma_f32_16x16x32_bf16(bh[n],  al4[m], acc[m][n], 0, 0, 0);
            }

        __syncthreads();               // one barrier/step: drains next-tile loads
        cur ^= 1;                      // (they had the whole MFMA phase to land)
    }
#undef STAGE

    // epilogue (swapped layout): i = base + m*16 + (l&15), j = base + n*16 + (l>>4)*4 + r
    int il = l & 15, q4 = (l >> 4) * 4;
    float sqi[4];
    float sqj[4][4];
#pragma unroll
    for (int m = 0; m < 4; ++m) sqi[m] = sq[gi0 + wm * 64 + m * 16 + il];
#pragma unroll
    for (int n = 0; n < 4; ++n)
#pragma unroll
        for (int r = 0; r < 4; ++r) sqj[n][r] = sq[j0 + wn * 64 + n * 16 + q4 + r];

#pragma unroll
    for (int m = 0; m < 4; ++m)
#pragma unroll
        for (int n = 0; n < 4; ++n) {
            float4 o;
            o.x = fmaxf(sqi[m] + sqj[n][0] - 2.f * acc[m][n][0], 0.f);
            o.y = fmaxf(sqi[m] + sqj[n][1] - 2.f * acc[m][n][1], 0.f);
            o.z = fmaxf(sqi[m] + sqj[n][2] - 2.f * acc[m][n][2], 0.f);
            o.w = fmaxf(sqi[m] + sqj[n][3] - 2.f * acc[m][n][3], 0.f);
            *(float4*)(dist + (size_t)(li0 + wm * 64 + m * 16 + il) * BN
                            + j0 + wn * 64 + n * 16 + q4) = o;
        }
}

// ---------------- K3: rank-26 select, one row/block, asm-pinned 32 values/lane -------
// asm volatile loads CANNOT be rematerialized (unlike plain loads: rounds 2-7
// all re-read the row ~26x through L2/L3); with only 8 uint4 = 32 VGPRs live,
// there is no spill pressure either (round-5 failure was 128 values spilling).
__global__ __launch_bounds__(256, 4)
void select_kernel(const float* __restrict__ dist, const float* __restrict__ maxg,
                   const int* __restrict__ hard, const int* __restrict__ kptr,
                   float* __restrict__ out, int row0) {
    __shared__ int scnt[2][4];
    __shared__ unsigned swmax[4];
    __shared__ int sbins[NCL];

    int t = threadIdx.x, w = t >> 6, l = t & 63;
    int li = blockIdx.x;               // chunk-local row (one block per row)
    if (t < NCL) sbins[t] = 0;

    uint4v U[8];
    const char* rb = (const char*)(dist + (size_t)li * BN) + (size_t)t * 16;
#pragma unroll
    for (int q = 0; q < 8; ++q) {
        const char* a = rb + q * 4096;
        asm volatile("global_load_dwordx4 %0, %1, off" : "=v"(U[q]) : "v"(a));
    }
    asm volatile("s_waitcnt vmcnt(0)" ::: "memory");
    __builtin_amdgcn_sched_barrier(0); // nothing hoists above the wait (rule #18)

    // block max -> search upper bound (d2 >= 0: uint order == float order)
    unsigned mx = 0u;
#pragma unroll
    for (int q = 0; q < 8; ++q)
#pragma unroll
        for (int c = 0; c < 4; ++c) mx = U[q][c] > mx ? U[q][c] : mx;
    for (int m = 32; m; m >>= 1) {
        unsigned ox = (unsigned)__shfl_xor((int)mx, m, 64);
        mx = ox > mx ? ox : mx;
    }
    if (l == 0) swmax[w] = mx;
    __syncthreads();
    mx = swmax[0];
    mx = swmax[1] > mx ? swmax[1] : mx;
    mx = swmax[2] > mx ? swmax[2] : mx;
    mx = swmax[3] > mx ? swmax[3] : mx;

    int topn = *kptr + 1;              // 26: thr = sorted[k]
    unsigned lo = 0u, hi = mx;
    int p = 0;
    while (lo < hi) {                  // lo/hi/tot block-uniform -> barrier legal
        unsigned mid = lo + ((hi - lo) >> 1);
        int cnt = 0;
#pragma unroll
        for (int q = 0; q < 8; ++q)
#pragma unroll
            for (int c = 0; c < 4; ++c)
                cnt += __popcll(__ballot(U[q][c] <= mid));  // v_cmp + SALU bcnt
        if (l == 0) scnt[p][w] = cnt;
        __syncthreads();               // slot p visible; p^1 writes can't collide
        int tot = scnt[p][0] + scnt[p][1] + scnt[p][2] + scnt[p][3];
        if (tot >= topn) hi = mid; else lo = mid + 1;
        p ^= 1;
    }
    unsigned thrb = lo;                // exact bit pattern of sorted[k] (d2 domain)

    // strict < thrb -> per-cluster counts (~26 hits/row -> rare LDS atomics)
#pragma unroll
    for (int q = 0; q < 8; ++q)
#pragma unroll
        for (int c = 0; c < 4; ++c)
            if (U[q][c] < thrb) {
                int j = (q * 256 + t) * 4 + c;
                atomicAdd(&sbins[hard[j]], 1);
            }
    __syncthreads();

    // entropy epilogue: wave 0, lanes 0..31 = clusters
    if (t < NCL) {
        int cnt = sbins[t];
        int n = cnt;
        for (int m = 16; m; m >>= 1) n += __shfl_xor(n, m, 64);
        float nf = (float)n;
        float b = (float)cnt / nf;
        float term = -b * logf(b + 1e-5f);
        for (int m = 16; m; m >>= 1) term += __shfl_xor(term, m, 64);
        if (t == 0) out[row0 + li] = term * maxg[row0 + li];
    }
}

extern "C" void kernel_launch(void* const* d_in, const int* in_sizes, int n_in,
                              void* d_out, int out_size, void* d_ws, size_t ws_size,
                              hipStream_t stream) {
    const float* enc = (const float*)d_in[0];
    const float* cat = (const float*)d_in[1];
    const int* kptr = (const int*)d_in[2];
    float* out = (float*)d_out;

    float* sq = (float*)d_ws;
    float* maxg = sq + BN;
    int* hard = (int*)(maxg + BN);
    ushort* eh = (ushort*)(hard + BN);
    ushort* el = eh + (size_t)BN * ENC;
    float* dist = (float*)(el + (size_t)BN * ENC);

    // Panel-cycle dist through L3: 2048x8192 fp32 = 64 MB buffer reused 4x, so
    // GEMM writes stay L3-resident for the immediately-following select reads.
    size_t head = (size_t)((char*)dist - (char*)d_ws);
    size_t avail = ws_size > head ? ws_size - head : 0;
    long max_rows = (long)(avail / ((size_t)BN * sizeof(float)));
    int chunk = PANEL;
    if (chunk > max_rows) chunk = (int)((max_rows / TM) * TM);
    if (chunk > BN) chunk = BN;
    if (chunk < TM) chunk = TM;

    prep_kernel<<<BN / 4, 256, 0, stream>>>(enc, cat, sq, maxg, hard, eh, el);

    for (int row0 = 0; row0 < BN; row0 += chunk) {
        int rows = BN - row0 < chunk ? BN - row0 : chunk;
        dim3 g(BN / TM, rows / TM);
        dist_mfma_kernel<<<g, 256, 0, stream>>>(eh, el, sq, dist, row0);
        select_kernel<<<rows, 256, 0, stream>>>(dist, maxg, hard, kptr, out, row0);
    }
}

// Round 9
// 338.174 us; speedup vs baseline: 1.7499x; 1.1911x over previous
//
#include <hip/hip_runtime.h>
#include <math.h>

#define BN 8192
#define ENC 256
#define NCL 32
#define TM 128
#define BK 32
#define PANEL 2048

typedef __attribute__((ext_vector_type(8))) short short8;   // bf16x8 fragment
typedef __attribute__((ext_vector_type(4))) float f32x4;
typedef __attribute__((ext_vector_type(4))) unsigned uint4v;

__device__ __forceinline__ ushort f2bf(float x) {           // RNE float->bf16
    unsigned b = __float_as_uint(x);
    return (ushort)((b + 0x7FFFu + ((b >> 16) & 1u)) >> 16);
}

__device__ __forceinline__ void async16(void* lds, const void* g) {
    __builtin_amdgcn_global_load_lds(
        (const __attribute__((address_space(1))) unsigned*)g,
        (__attribute__((address_space(3))) unsigned*)lds, 16, 0, 0);
}

// ---------------- K1: sumsq + cat argmax + bf16 hi/lo split (granule-swizzled) ----------
// Swizzle for BK=32: within each 32-elem K-slice (4 granules of 16B), granule
// g -> g ^ ((row>>1)&3). Read-side applies the same XOR (rule #21).
__global__ void prep_kernel(const float* __restrict__ enc, const float* __restrict__ cat,
                            float* __restrict__ sq, float* __restrict__ maxg,
                            int* __restrict__ hard, ushort* __restrict__ eh,
                            ushort* __restrict__ el) {
    int w = threadIdx.x >> 6, l = threadIdx.x & 63;
    int row = blockIdx.x * 4 + w;
    const float4* e4 = (const float4*)(enc + (size_t)row * ENC);
    float4 v = e4[l];  // elements 4l..4l+3
    float s = v.x * v.x + v.y * v.y + v.z * v.z + v.w * v.w;
    for (int m = 32; m; m >>= 1) s += __shfl_xor(s, m, 64);

    ushort4 hh, ll;
    hh.x = f2bf(v.x); ll.x = f2bf(v.x - __uint_as_float((unsigned)hh.x << 16));
    hh.y = f2bf(v.y); ll.y = f2bf(v.y - __uint_as_float((unsigned)hh.y << 16));
    hh.z = f2bf(v.z); ll.z = f2bf(v.z - __uint_as_float((unsigned)hh.z << 16));
    hh.w = f2bf(v.w); ll.w = f2bf(v.w - __uint_as_float((unsigned)hh.w << 16));
    int g = l >> 1;                                       // original granule 0..31
    int gs = (g & ~3) | ((g & 3) ^ ((row >> 1) & 3));     // swizzled within group-of-4
    int kp = gs * 8 + (l & 1) * 4;                        // element offset in row
    *(ushort4*)(eh + (size_t)row * ENC + kp) = hh;
    *(ushort4*)(el + (size_t)row * ENC + kp) = ll;

    float cv = (l < NCL) ? cat[(size_t)row * NCL + l] : -__builtin_huge_valf();
    int ci = (l < NCL) ? l : 0x7fffffff;
    for (int m = 32; m; m >>= 1) {
        float ov = __shfl_xor(cv, m, 64);
        int oi = __shfl_xor(ci, m, 64);
        if (ov > cv || (ov == cv && oi < ci)) { cv = ov; ci = oi; }
    }
    if (l == 0) { sq[row] = s; maxg[row] = cv; hard[row] = ci; }
}

// ---------------- K2: pipelined split-bf16 MFMA distance GEMM -------------------------
// 2-phase pipeline: double-buffered LDS, BK=32, 8 K-steps, stage k+1 issued
// before computing k. NEW: column-strip XCD mapping — each XCD owns 8 bx tiles
// x all by, so its working set (A panel 2 MB + B strip 1 MB) fits its 4 MB L2.
// Round-8 mapping gave each XCD the FULL 8 MB B panel -> L3-latency-bound.
__global__ __launch_bounds__(256, 2)
void dist_mfma_kernel(const ushort* __restrict__ eh, const ushort* __restrict__ el,
                      const float* __restrict__ sq, float* __restrict__ dist, int row0) {
    __shared__ __align__(16) ushort lds[2][4 * TM * BK];  // 2 bufs x 32KB (Ah Al Bh Bl)

    int t = threadIdx.x, w = t >> 6, l = t & 63;
    int wm = w >> 1, wn = w & 1;

    // column-strip XCD mapping (bijective for gx % 8 == 0; gx = 64 here)
    int gx = gridDim.x;
    int bid = blockIdx.y * gx + blockIdx.x;
    int xcd = bid & 7, i = bid >> 3;
    int strip = gx >> 3;               // 8 bx tiles per XCD
    int bx = xcd * strip + (i % strip);
    int by = i / strip;

    int li0 = by * TM;                 // chunk-local A rows (dist)
    int gi0 = row0 + li0;              // global A rows
    int j0 = bx * TM;                  // global B rows / dist cols

    f32x4 acc[4][4];
#pragma unroll
    for (int m = 0; m < 4; ++m)
#pragma unroll
        for (int n = 0; n < 4; ++n) acc[m][n] = (f32x4){0.f, 0.f, 0.f, 0.f};

    int srow = w * 32 + (l >> 2);      // staging row (+ q*16), wave covers 32 rows
    int sg = (l & 3) * 8;              // granule elem offset within K-slice

#define STAGE(BUF, K0)                                                       \
    do {                                                                     \
        _Pragma("unroll") for (int q_ = 0; q_ < 2; ++q_) {                   \
            int r_ = srow + q_ * 16;                                         \
            size_t ga_ = (size_t)(gi0 + r_) * ENC + (K0) + sg;               \
            size_t gb_ = (size_t)(j0 + r_) * ENC + (K0) + sg;                \
            int ldo_ = r_ * BK + sg;                                         \
            async16(&lds[BUF][0 * TM * BK + ldo_], eh + ga_);                \
            async16(&lds[BUF][1 * TM * BK + ldo_], el + ga_);                \
            async16(&lds[BUF][2 * TM * BK + ldo_], eh + gb_);                \
            async16(&lds[BUF][3 * TM * BK + ldo_], el + gb_);                \
        }                                                                    \
    } while (0)

    STAGE(0, 0);
    __syncthreads();                   // prologue: wait first tile (full latency once)

    int cur = 0;
    for (int k0 = 0; k0 < ENC; k0 += BK) {
        if (k0 + BK < ENC) STAGE(cur ^ 1, k0 + BK);   // issue next tile FIRST

        const ushort* Ah = &lds[cur][0];
        const ushort* Al = Ah + TM * BK;
        const ushort* Bh = Ah + 2 * TM * BK;
        const ushort* Bl = Ah + 3 * TM * BK;

        short8 ah[4], al4[4], bh[4], bl4[4];
#pragma unroll
        for (int m = 0; m < 4; ++m) {
            int R = wm * 64 + m * 16 + (l & 15);
            int gl = (l >> 4) ^ ((R >> 1) & 3);       // un-swizzle on read
            ah[m]  = *(const short8*)(Ah + R * BK + gl * 8);
            al4[m] = *(const short8*)(Al + R * BK + gl * 8);
        }
#pragma unroll
        for (int n = 0; n < 4; ++n) {
            int R = wn * 64 + n * 16 + (l & 15);
            int gl = (l >> 4) ^ ((R >> 1) & 3);
            bh[n]  = *(const short8*)(Bh + R * BK + gl * 8);
            bl4[n] = *(const short8*)(Bl + R * BK + gl * 8);
        }
        // swapped operands: D[col=l&15 -> dist row][reg -> dist col]
#pragma unroll
        for (int m = 0; m < 4; ++m)
#pragma unroll
            for (int n = 0; n < 4; ++n) {
                acc[m][n] = __builtin_amdgcn_mfma_f32_16x16x32_bf16(bh[n],  ah[m],  acc[m][n], 0, 0, 0);
                acc[m][n] = __builtin_amdgcn_mfma_f32_16x16x32_bf16(bl4[n], ah[m],  acc[m][n], 0, 0, 0);
                acc[m][n] = __builtin_amdgcn_mfma_f32_16x16x32_bf16(bh[n],  al4[m], acc[m][n], 0, 0, 0);
            }

        __syncthreads();               // one barrier/step: drains next-tile loads
        cur ^= 1;                      // (they had the whole MFMA phase to land)
    }
#undef STAGE

    // epilogue (swapped layout): i = base + m*16 + (l&15), j = base + n*16 + (l>>4)*4 + r
    int il = l & 15, q4 = (l >> 4) * 4;
    float sqi[4];
    float sqj[4][4];
#pragma unroll
    for (int m = 0; m < 4; ++m) sqi[m] = sq[gi0 + wm * 64 + m * 16 + il];
#pragma unroll
    for (int n = 0; n < 4; ++n)
#pragma unroll
        for (int r = 0; r < 4; ++r) sqj[n][r] = sq[j0 + wn * 64 + n * 16 + q4 + r];

#pragma unroll
    for (int m = 0; m < 4; ++m)
#pragma unroll
        for (int n = 0; n < 4; ++n) {
            float4 o;
            o.x = fmaxf(sqi[m] + sqj[n][0] - 2.f * acc[m][n][0], 0.f);
            o.y = fmaxf(sqi[m] + sqj[n][1] - 2.f * acc[m][n][1], 0.f);
            o.z = fmaxf(sqi[m] + sqj[n][2] - 2.f * acc[m][n][2], 0.f);
            o.w = fmaxf(sqi[m] + sqj[n][3] - 2.f * acc[m][n][3], 0.f);
            *(float4*)(dist + (size_t)(li0 + wm * 64 + m * 16 + il) * BN
                            + j0 + wn * 64 + n * 16 + q4) = o;
        }
}

// ---------------- K3: LDS-staged ballot select with early-exit compaction -------------
// Rounds 2-8 lesson: the compiler will NOT keep a row working set in VGPRs
// across a runtime-trip-count barrier loop (remat or spill, every time). So the
// row lives in LDS (32 KB): probes re-scan LDS (8 ds_read_b128/thread, ~0.1 us);
// as soon as count(<=hi) <= 64, the candidates are compacted to wave 0's lanes
// and the search finishes fully in-register. No histograms (round-4 conflict
// storm), exact rank semantics.
__global__ __launch_bounds__(256, 4)
void select_kernel(const float* __restrict__ dist, const float* __restrict__ maxg,
                   const int* __restrict__ hard, const int* __restrict__ kptr,
                   float* __restrict__ out, int row0) {
    __shared__ __align__(16) unsigned srow[BN];   // 32 KB staged d2 bit patterns
    __shared__ int scnt[2][4];
    __shared__ unsigned swmax[4];
    __shared__ int sbins[NCL];
    __shared__ unsigned cand[64];
    __shared__ int ccnt;
    __shared__ unsigned sthr;

    int t = threadIdx.x, w = t >> 6, l = t & 63;
    int li = blockIdx.x;               // chunk-local row (one block per row)
    if (t < NCL) sbins[t] = 0;
    if (t == 0) ccnt = 0;

    uint4v* S4 = (uint4v*)srow;
    const uint4v* rd = (const uint4v*)(dist + (size_t)li * BN);

    // stage + block max (d2 >= 0: uint order == float order)
    unsigned mx = 0u;
#pragma unroll
    for (int q = 0; q < 8; ++q) {
        uint4v v = rd[q * 256 + t];
        S4[q * 256 + t] = v;           // contiguous b128 writes: conflict-free
#pragma unroll
        for (int c = 0; c < 4; ++c) mx = v[c] > mx ? v[c] : mx;
    }
    for (int m = 32; m; m >>= 1) {
        unsigned ox = (unsigned)__shfl_xor((int)mx, m, 64);
        mx = ox > mx ? ox : mx;
    }
    if (l == 0) swmax[w] = mx;
    __syncthreads();                   // also publishes srow
    mx = swmax[0];
    mx = swmax[1] > mx ? swmax[1] : mx;
    mx = swmax[2] > mx ? swmax[2] : mx;
    mx = swmax[3] > mx ? swmax[3] : mx;

    int topn = *kptr + 1;              // 26: thr = sorted[k]
    unsigned lo = 0u, hi = mx;
    int cnt_hi = BN;                   // count(<= hi); invariant cnt_hi >= topn
    int p = 0;
    bool compacted = false;
    while (lo < hi) {                  // block-uniform bounds -> barriers legal
        unsigned mid = lo + ((hi - lo) >> 1);
        int cnt = 0;
#pragma unroll
        for (int q = 0; q < 8; ++q) {
            uint4v u = S4[q * 256 + t];
#pragma unroll
            for (int c = 0; c < 4; ++c)
                cnt += __popcll(__ballot(u[c] <= mid));
        }
        if (l == 0) scnt[p][w] = cnt;
        __syncthreads();               // slot p visible; p^1 writes can't collide
        int tot = scnt[p][0] + scnt[p][1] + scnt[p][2] + scnt[p][3];
        if (tot >= topn) { hi = mid; cnt_hi = tot; } else lo = mid + 1;
        p ^= 1;
        if (cnt_hi <= 64) { compacted = true; break; }  // block-uniform
    }

    unsigned thrb;
    if (compacted) {
        // gather candidates (<= hi, exactly cnt_hi <= 64 of them) into cand[]
#pragma unroll
        for (int q = 0; q < 8; ++q) {
            uint4v u = S4[q * 256 + t];
#pragma unroll
            for (int c = 0; c < 4; ++c)
                if (u[c] <= hi) cand[atomicAdd(&ccnt, 1)] = u[c];
        }
        __syncthreads();
        if (w == 0) {                  // finish search in-register on one wave
            int nc = ccnt;
            unsigned v = (l < nc) ? cand[l] : 0xFFFFFFFFu;
            unsigned l2 = lo, h2 = hi;
            while (l2 < h2) {
                unsigned mid = l2 + ((h2 - l2) >> 1);
                int c = __popcll(__ballot(l < nc && v <= mid));
                if (c >= topn) h2 = mid; else l2 = mid + 1;
            }
            if (l == 0) sthr = l2;
        }
        __syncthreads();
        thrb = sthr;
    } else {
        thrb = lo;                     // converged exactly in the full search
    }

    // strict < thrb -> per-cluster counts (~26 hits/row -> rare LDS atomics)
#pragma unroll
    for (int q = 0; q < 8; ++q) {
        uint4v u = S4[q * 256 + t];
#pragma unroll
        for (int c = 0; c < 4; ++c)
            if (u[c] < thrb) {
                int j = (q * 256 + t) * 4 + c;
                atomicAdd(&sbins[hard[j]], 1);
            }
    }
    __syncthreads();

    // entropy epilogue: wave 0, lanes 0..31 = clusters
    if (t < NCL) {
        int cnt = sbins[t];
        int n = cnt;
        for (int m = 16; m; m >>= 1) n += __shfl_xor(n, m, 64);
        float nf = (float)n;
        float b = (float)cnt / nf;
        float term = -b * logf(b + 1e-5f);
        for (int m = 16; m; m >>= 1) term += __shfl_xor(term, m, 64);
        if (t == 0) out[row0 + li] = term * maxg[row0 + li];
    }
}

extern "C" void kernel_launch(void* const* d_in, const int* in_sizes, int n_in,
                              void* d_out, int out_size, void* d_ws, size_t ws_size,
                              hipStream_t stream) {
    const float* enc = (const float*)d_in[0];
    const float* cat = (const float*)d_in[1];
    const int* kptr = (const int*)d_in[2];
    float* out = (float*)d_out;

    float* sq = (float*)d_ws;
    float* maxg = sq + BN;
    int* hard = (int*)(maxg + BN);
    ushort* eh = (ushort*)(hard + BN);
    ushort* el = eh + (size_t)BN * ENC;
    float* dist = (float*)(el + (size_t)BN * ENC);

    // Panel-cycle dist through L3: 2048x8192 fp32 = 64 MB buffer reused 4x, so
    // GEMM writes stay L3-resident for the immediately-following select reads.
    size_t head = (size_t)((char*)dist - (char*)d_ws);
    size_t avail = ws_size > head ? ws_size - head : 0;
    long max_rows = (long)(avail / ((size_t)BN * sizeof(float)));
    int chunk = PANEL;
    if (chunk > max_rows) chunk = (int)((max_rows / TM) * TM);
    if (chunk > BN) chunk = BN;
    if (chunk < TM) chunk = TM;

    prep_kernel<<<BN / 4, 256, 0, stream>>>(enc, cat, sq, maxg, hard, eh, el);

    for (int row0 = 0; row0 < BN; row0 += chunk) {
        int rows = BN - row0 < chunk ? BN - row0 : chunk;
        dim3 g(BN / TM, rows / TM);
        dist_mfma_kernel<<<g, 256, 0, stream>>>(eh, el, sq, dist, row0);
        select_kernel<<<rows, 256, 0, stream>>>(dist, maxg, hard, kptr, out, row0);
    }
}

// Round 10
// 325.139 us; speedup vs baseline: 1.8201x; 1.0401x over previous
//
#include <hip/hip_runtime.h>
#include <math.h>

#define BN 8192
#define ENC 256
#define NCL 32
#define TM 128
#define BK 32
#define PANEL 2048
#define CCAP 1024

typedef __attribute__((ext_vector_type(8))) short short8;   // bf16x8 fragment
typedef __attribute__((ext_vector_type(4))) float f32x4;
typedef __attribute__((ext_vector_type(4))) unsigned uint4v;

__device__ __forceinline__ ushort f2bf(float x) {           // RNE float->bf16
    unsigned b = __float_as_uint(x);
    return (ushort)((b + 0x7FFFu + ((b >> 16) & 1u)) >> 16);
}

__device__ __forceinline__ void async16(void* lds, const void* g) {
    __builtin_amdgcn_global_load_lds(
        (const __attribute__((address_space(1))) unsigned*)g,
        (__attribute__((address_space(3))) unsigned*)lds, 16, 0, 0);
}

// ---------------- K1: sumsq + cat argmax + bf16 hi/lo split (granule-swizzled) ----------
// Swizzle for BK=32: within each 32-elem K-slice (4 granules of 16B), granule
// g -> g ^ ((row>>1)&3). Read-side applies the same XOR (rule #21).
__global__ void prep_kernel(const float* __restrict__ enc, const float* __restrict__ cat,
                            float* __restrict__ sq, float* __restrict__ maxg,
                            int* __restrict__ hard, ushort* __restrict__ eh,
                            ushort* __restrict__ el) {
    int w = threadIdx.x >> 6, l = threadIdx.x & 63;
    int row = blockIdx.x * 4 + w;
    const float4* e4 = (const float4*)(enc + (size_t)row * ENC);
    float4 v = e4[l];  // elements 4l..4l+3
    float s = v.x * v.x + v.y * v.y + v.z * v.z + v.w * v.w;
    for (int m = 32; m; m >>= 1) s += __shfl_xor(s, m, 64);

    ushort4 hh, ll;
    hh.x = f2bf(v.x); ll.x = f2bf(v.x - __uint_as_float((unsigned)hh.x << 16));
    hh.y = f2bf(v.y); ll.y = f2bf(v.y - __uint_as_float((unsigned)hh.y << 16));
    hh.z = f2bf(v.z); ll.z = f2bf(v.z - __uint_as_float((unsigned)hh.z << 16));
    hh.w = f2bf(v.w); ll.w = f2bf(v.w - __uint_as_float((unsigned)hh.w << 16));
    int g = l >> 1;                                       // original granule 0..31
    int gs = (g & ~3) | ((g & 3) ^ ((row >> 1) & 3));     // swizzled within group-of-4
    int kp = gs * 8 + (l & 1) * 4;                        // element offset in row
    *(ushort4*)(eh + (size_t)row * ENC + kp) = hh;
    *(ushort4*)(el + (size_t)row * ENC + kp) = ll;

    float cv = (l < NCL) ? cat[(size_t)row * NCL + l] : -__builtin_huge_valf();
    int ci = (l < NCL) ? l : 0x7fffffff;
    for (int m = 32; m; m >>= 1) {
        float ov = __shfl_xor(cv, m, 64);
        int oi = __shfl_xor(ci, m, 64);
        if (ov > cv || (ov == cv && oi < ci)) { cv = ov; ci = oi; }
    }
    if (l == 0) { sq[row] = s; maxg[row] = cv; hard[row] = ci; }
}

// ---------------- K2: pipelined split-bf16 MFMA distance GEMM -------------------------
// 2-phase pipeline: double-buffered LDS, BK=32, 8 K-steps, stage k+1 issued
// before computing k. Column-strip XCD mapping: each XCD owns 8 bx tiles x all
// by, so its working set (A panel 2 MB + B strip 1 MB) fits its 4 MB L2.
__global__ __launch_bounds__(256, 2)
void dist_mfma_kernel(const ushort* __restrict__ eh, const ushort* __restrict__ el,
                      const float* __restrict__ sq, float* __restrict__ dist, int row0) {
    __shared__ __align__(16) ushort lds[2][4 * TM * BK];  // 2 bufs x 32KB (Ah Al Bh Bl)

    int t = threadIdx.x, w = t >> 6, l = t & 63;
    int wm = w >> 1, wn = w & 1;

    // column-strip XCD mapping (bijective for gx % 8 == 0; gx = 64 here)
    int gx = gridDim.x;
    int bid = blockIdx.y * gx + blockIdx.x;
    int xcd = bid & 7, i = bid >> 3;
    int strip = gx >> 3;               // 8 bx tiles per XCD
    int bx = xcd * strip + (i % strip);
    int by = i / strip;

    int li0 = by * TM;                 // chunk-local A rows (dist)
    int gi0 = row0 + li0;              // global A rows
    int j0 = bx * TM;                  // global B rows / dist cols

    f32x4 acc[4][4];
#pragma unroll
    for (int m = 0; m < 4; ++m)
#pragma unroll
        for (int n = 0; n < 4; ++n) acc[m][n] = (f32x4){0.f, 0.f, 0.f, 0.f};

    int srow = w * 32 + (l >> 2);      // staging row (+ q*16), wave covers 32 rows
    int sg = (l & 3) * 8;              // granule elem offset within K-slice

#define STAGE(BUF, K0)                                                       \
    do {                                                                     \
        _Pragma("unroll") for (int q_ = 0; q_ < 2; ++q_) {                   \
            int r_ = srow + q_ * 16;                                         \
            size_t ga_ = (size_t)(gi0 + r_) * ENC + (K0) + sg;               \
            size_t gb_ = (size_t)(j0 + r_) * ENC + (K0) + sg;                \
            int ldo_ = r_ * BK + sg;                                         \
            async16(&lds[BUF][0 * TM * BK + ldo_], eh + ga_);                \
            async16(&lds[BUF][1 * TM * BK + ldo_], el + ga_);                \
            async16(&lds[BUF][2 * TM * BK + ldo_], eh + gb_);                \
            async16(&lds[BUF][3 * TM * BK + ldo_], el + gb_);                \
        }                                                                    \
    } while (0)

    STAGE(0, 0);
    __syncthreads();                   // prologue: wait first tile (full latency once)

    int cur = 0;
    for (int k0 = 0; k0 < ENC; k0 += BK) {
        if (k0 + BK < ENC) STAGE(cur ^ 1, k0 + BK);   // issue next tile FIRST

        const ushort* Ah = &lds[cur][0];
        const ushort* Al = Ah + TM * BK;
        const ushort* Bh = Ah + 2 * TM * BK;
        const ushort* Bl = Ah + 3 * TM * BK;

        short8 ah[4], al4[4], bh[4], bl4[4];
#pragma unroll
        for (int m = 0; m < 4; ++m) {
            int R = wm * 64 + m * 16 + (l & 15);
            int gl = (l >> 4) ^ ((R >> 1) & 3);       // un-swizzle on read
            ah[m]  = *(const short8*)(Ah + R * BK + gl * 8);
            al4[m] = *(const short8*)(Al + R * BK + gl * 8);
        }
#pragma unroll
        for (int n = 0; n < 4; ++n) {
            int R = wn * 64 + n * 16 + (l & 15);
            int gl = (l >> 4) ^ ((R >> 1) & 3);
            bh[n]  = *(const short8*)(Bh + R * BK + gl * 8);
            bl4[n] = *(const short8*)(Bl + R * BK + gl * 8);
        }
        // swapped operands: D[col=l&15 -> dist row][reg -> dist col]
#pragma unroll
        for (int m = 0; m < 4; ++m)
#pragma unroll
            for (int n = 0; n < 4; ++n) {
                acc[m][n] = __builtin_amdgcn_mfma_f32_16x16x32_bf16(bh[n],  ah[m],  acc[m][n], 0, 0, 0);
                acc[m][n] = __builtin_amdgcn_mfma_f32_16x16x32_bf16(bl4[n], ah[m],  acc[m][n], 0, 0, 0);
                acc[m][n] = __builtin_amdgcn_mfma_f32_16x16x32_bf16(bh[n],  al4[m], acc[m][n], 0, 0, 0);
            }

        __syncthreads();               // one barrier/step: drains next-tile loads
        cur ^= 1;                      // (they had the whole MFMA phase to land)
    }
#undef STAGE

    // epilogue (swapped layout): i = base + m*16 + (l&15), j = base + n*16 + (l>>4)*4 + r
    int il = l & 15, q4 = (l >> 4) * 4;
    float sqi[4];
    float sqj[4][4];
#pragma unroll
    for (int m = 0; m < 4; ++m) sqi[m] = sq[gi0 + wm * 64 + m * 16 + il];
#pragma unroll
    for (int n = 0; n < 4; ++n)
#pragma unroll
        for (int r = 0; r < 4; ++r) sqj[n][r] = sq[j0 + wn * 64 + n * 16 + q4 + r];

#pragma unroll
    for (int m = 0; m < 4; ++m)
#pragma unroll
        for (int n = 0; n < 4; ++n) {
            float4 o;
            o.x = fmaxf(sqi[m] + sqj[n][0] - 2.f * acc[m][n][0], 0.f);
            o.y = fmaxf(sqi[m] + sqj[n][1] - 2.f * acc[m][n][1], 0.f);
            o.z = fmaxf(sqi[m] + sqj[n][2] - 2.f * acc[m][n][2], 0.f);
            o.w = fmaxf(sqi[m] + sqj[n][3] - 2.f * acc[m][n][3], 0.f);
            *(float4*)(dist + (size_t)(li0 + wm * 64 + m * 16 + il) * BN
                            + j0 + wn * 64 + n * 16 + q4) = o;
        }
}

// ---------------- K3: sampling-pivot exact rank select + entropy ----------------------
// Pivot = rank-8 of 256 row samples (expected row-rank ~255). One full-row pass
// compacts (value, idx) of everything < pivot into LDS (~255 entries); the
// rank-topn bisection then probes a padded 1024-entry array (1 ds_read_b128 per
// thread per probe, vs round-9's 25 full 32KB scans), and the cluster-bin pass
// touches candidates only. If count < topn or > CCAP (P ~ 1e-6), exact fallback
// search over the global row — semantics exact for every row.
__global__ __launch_bounds__(256, 4)
void select_kernel(const float* __restrict__ dist, const float* __restrict__ maxg,
                   const int* __restrict__ hard, const int* __restrict__ kptr,
                   float* __restrict__ out, int row0) {
    __shared__ __align__(16) unsigned samp[256];
    __shared__ __align__(16) unsigned cval[CCAP];
    __shared__ int cidx[CCAP];
    __shared__ int scnt[2][4];
    __shared__ int sbins[NCL];
    __shared__ unsigned spiv;
    __shared__ int ccnt;

    int t = threadIdx.x, w = t >> 6, l = t & 63;
    int li = blockIdx.x;               // chunk-local row (one block per row)
    const unsigned* rowu = (const unsigned*)(dist + (size_t)li * BN);
    const uint4v* rd = (const uint4v*)rowu;

    if (t < NCL) sbins[t] = 0;
    if (t == 0) ccnt = 0;
    cval[t] = 0xFFFFFFFFu; cval[t + 256] = 0xFFFFFFFFu;   // pad: compares false
    cval[t + 512] = 0xFFFFFFFFu; cval[t + 768] = 0xFFFFFFFFu;
    samp[t] = rowu[2048 + t];          // contiguous sample (iid row entries)
    __syncthreads();

    int topn = *kptr + 1;              // 26: thr = sorted[k]
    int r = topn / 16 + 1; if (r < 8) r = 8;  // sample rank: E[count] ~ 32r

    if (w == 0) {                      // wave-0 pivot search (4 samples/lane)
        uint4v sv = ((const uint4v*)samp)[l];
        unsigned lo = 0u, hi = 0x7F800000u;
        while (lo < hi) {              // wave-uniform: no block sync needed
            unsigned mid = lo + ((hi - lo) >> 1);
            int c = 0;
#pragma unroll
            for (int e = 0; e < 4; ++e) c += __popcll(__ballot(sv[e] <= mid));
            if (c >= r) hi = mid; else lo = mid + 1;
        }
        if (l == 0) spiv = lo;         // rank-r sample value (bit pattern)
    }
    __syncthreads();
    unsigned piv = spiv;

    // single full-row pass: compact strict-< pivot candidates (value, index)
#pragma unroll
    for (int q = 0; q < 8; ++q) {
        uint4v u = rd[q * 256 + t];
#pragma unroll
        for (int c = 0; c < 4; ++c)
            if (u[c] < piv) {
                int pos = atomicAdd(&ccnt, 1);
                if (pos < CCAP) { cval[pos] = u[c]; cidx[pos] = (q * 256 + t) * 4 + c; }
            }
    }
    __syncthreads();
    int nc = ccnt;                     // exact count(< piv), block-uniform
    bool ok = (nc >= topn) && (nc <= CCAP);

    unsigned thr;
    if (ok) {
        // rank-topn among candidates == row rank-topn (all topn smallest < piv)
        int p = 0;
        unsigned lo = 0u, hi = piv;
        while (lo < hi) {
            unsigned mid = lo + ((hi - lo) >> 1);
            uint4v cv = ((const uint4v*)cval)[t];   // 1 b128/thread/probe
            int cnt = 0;
#pragma unroll
            for (int c = 0; c < 4; ++c) cnt += __popcll(__ballot(cv[c] <= mid));
            if (l == 0) scnt[p][w] = cnt;
            __syncthreads();           // parity slots: 1 barrier/probe (r8 proven)
            int tot = scnt[p][0] + scnt[p][1] + scnt[p][2] + scnt[p][3];
            if (tot >= topn) hi = mid; else lo = mid + 1;
            p ^= 1;
        }
        thr = lo;
    } else {
        // exact fallback: bisection over the global row (L3-hot), ~never taken
        int p = 0;
        unsigned lo = 0u, hi = 0x7F800000u;
        while (lo < hi) {
            unsigned mid = lo + ((hi - lo) >> 1);
            int cnt = 0;
#pragma unroll
            for (int q = 0; q < 8; ++q) {
                uint4v u = rd[q * 256 + t];
#pragma unroll
                for (int c = 0; c < 4; ++c)
                    cnt += __popcll(__ballot(u[c] <= mid));
            }
            if (l == 0) scnt[p][w] = cnt;
            __syncthreads();
            int tot = scnt[p][0] + scnt[p][1] + scnt[p][2] + scnt[p][3];
            if (tot >= topn) hi = mid; else lo = mid + 1;
            p ^= 1;
        }
        thr = lo;
    }

    // strict < thr -> per-cluster counts (candidates only on the fast path)
    if (ok) {
        for (int pos = t; pos < nc; pos += 256)
            if (cval[pos] < thr) atomicAdd(&sbins[hard[cidx[pos]]], 1);
    } else {
#pragma unroll
        for (int q = 0; q < 8; ++q) {
            uint4v u = rd[q * 256 + t];
#pragma unroll
            for (int c = 0; c < 4; ++c)
                if (u[c] < thr) atomicAdd(&sbins[hard[(q * 256 + t) * 4 + c]], 1);
        }
    }
    __syncthreads();

    // entropy epilogue: wave 0, lanes 0..31 = clusters
    if (t < NCL) {
        int cnt = sbins[t];
        int n = cnt;
        for (int m = 16; m; m >>= 1) n += __shfl_xor(n, m, 64);
        float nf = (float)n;
        float b = (float)cnt / nf;
        float term = -b * logf(b + 1e-5f);
        for (int m = 16; m; m >>= 1) term += __shfl_xor(term, m, 64);
        if (t == 0) out[row0 + li] = term * maxg[row0 + li];
    }
}

extern "C" void kernel_launch(void* const* d_in, const int* in_sizes, int n_in,
                              void* d_out, int out_size, void* d_ws, size_t ws_size,
                              hipStream_t stream) {
    const float* enc = (const float*)d_in[0];
    const float* cat = (const float*)d_in[1];
    const int* kptr = (const int*)d_in[2];
    float* out = (float*)d_out;

    float* sq = (float*)d_ws;
    float* maxg = sq + BN;
    int* hard = (int*)(maxg + BN);
    ushort* eh = (ushort*)(hard + BN);
    ushort* el = eh + (size_t)BN * ENC;
    float* dist = (float*)(el + (size_t)BN * ENC);

    // Panel-cycle dist through L3: 2048x8192 fp32 = 64 MB buffer reused 4x, so
    // GEMM writes stay L3-resident for the immediately-following select reads.
    size_t head = (size_t)((char*)dist - (char*)d_ws);
    size_t avail = ws_size > head ? ws_size - head : 0;
    long max_rows = (long)(avail / ((size_t)BN * sizeof(float)));
    int chunk = PANEL;
    if (chunk > max_rows) chunk = (int)((max_rows / TM) * TM);
    if (chunk > BN) chunk = BN;
    if (chunk < TM) chunk = TM;

    prep_kernel<<<BN / 4, 256, 0, stream>>>(enc, cat, sq, maxg, hard, eh, el);

    for (int row0 = 0; row0 < BN; row0 += chunk) {
        int rows = BN - row0 < chunk ? BN - row0 : chunk;
        dim3 g(BN / TM, rows / TM);
        dist_mfma_kernel<<<g, 256, 0, stream>>>(eh, el, sq, dist, row0);
        select_kernel<<<rows, 256, 0, stream>>>(dist, maxg, hard, kptr, out, row0);
    }
}